// Round 1
// 1135.412 us; speedup vs baseline: 1.2389x; 1.2389x over previous
//
#include <hip/hip_runtime.h>
#include <hip/hip_bf16.h>
#include <cstdint>

using bf16 = __hip_bfloat16;
typedef __attribute__((ext_vector_type(8))) short bf16x8;   // MFMA A/B frag (4 VGPRs)
typedef __attribute__((ext_vector_type(4))) float f32x4;    // MFMA C/D frag

#define NB 16
#define NT_ 1024
#define ND 1024
#define NH 4096
#define NM (NB * NT_)   // 16384 rows

enum { EPI_BF16 = 0, EPI_OM, EPI_U, EPI_GELU, EPI_GELU_MUL, EPI_X1, EPI_X2 };

__device__ __forceinline__ float sigm(float x) { return 1.0f / (1.0f + expf(-x)); }
__device__ __forceinline__ float gelu_f(float x) { return 0.5f * x * (1.0f + erff(x * 0.7071067811865476f)); }
__device__ __forceinline__ float b2f(bf16 h) { return __bfloat162float(h); }
__device__ __forceinline__ bf16  f2b(float x) { return __float2bfloat16(x); }

__device__ __forceinline__ void gl_lds16(const bf16* g, void* l) {
  __builtin_amdgcn_global_load_lds((const __attribute__((address_space(1))) void*)g,
                                   (__attribute__((address_space(3))) void*)l, 16, 0, 0);
}

// ============================================================================
// 256x256 8-phase bf16 NT-GEMM (m201-style template, plain HIP)
//   C[m,n] = sum_k A[m,k]*Bw[n,k], fused epilogues.
//   BM=BN=256, BK=64, 512 threads (8 waves, 2M x 4N), per-wave C = 128x64.
//   LDS: 2 x (A 32K + B 32K) = 128 KiB, layout [kh][256 rows][32 k] per panel,
//        st_16x32 swizzle: byte ^= ((byte>>9)&1)<<5  (k-chunk ^= row.bit3<<1),
//        applied on the *global source* for global_load_lds (linear dest) and
//        on the ds_read address (both-sides-or-neither, rule 21).
//   Schedule per K-tile (4 phases):
//     ph0: read ALL B (8 b128) + A i{0,1} (4); stage A-hi(t+1)->other buf
//     ph1: read A i{2,3};                      stage B-lo(t+2)->cur buf (B consumed in ph0)
//     ph2: read A i{4..7};                     stage B-hi(t+2)->cur buf
//     ph3: (regs ready);                       stage A-lo(t+2)->cur buf (A consumed by ph2)
//     each phase: raw s_barrier; lgkmcnt(0); setprio(1); 16 MFMA; setprio(0); s_barrier
//   Boundary: vmcnt(6) (= 3 half-tiles x 2 loads in flight), vmcnt(0) only at tail.
// ============================================================================
template <int EPI>
__global__ __launch_bounds__(512, 2)
void gemm256(const bf16* __restrict__ A, const bf16* __restrict__ Bw,
             int M, int N, int K,
             const float* __restrict__ biasf, const float* __restrict__ vecf,
             const bf16* __restrict__ auxb, const bf16* __restrict__ auxb2,
             const float* __restrict__ auxf,
             float* __restrict__ outf, bf16* __restrict__ outb)
{
  (void)M;
  __shared__ __align__(16) char lds[131072];
  const int tid  = (int)threadIdx.x;
  const int wave = tid >> 6, lane = tid & 63;
  const int lr = lane & 15, lq = lane >> 4;
  const int wm = wave >> 2, wn = wave & 3;

  // XCD-aware bijective swizzle (gridDim.x % 8 == 0 for all launches here)
  const int nwg = (int)gridDim.x;
  const int swz = ((int)blockIdx.x & 7) * (nwg >> 3) + ((int)blockIdx.x >> 3);
  const int nbx = N >> 8;
  const int by = swz / nbx, bx = swz - by * nbx;
  const int m0 = by << 8, n0 = bx << 8;
  const int NT = K >> 6;

  const bf16* __restrict__ Ag = A  + (long)m0 * K;
  const bf16* __restrict__ Bg = Bw + (long)n0 * K;

  // staging constants: each wave stages 2 x 1KB chunks per half-tile
  const int lrow = lane >> 2;                                // row within 16-row chunk
  const int kbs  = (lane & 3) ^ (((lane >> 5) & 1) << 1);    // pre-swizzled source k-chunk
  // read constants (per-thread LDS byte offsets, swizzled)
  const int rswz   = (lq * 16) ^ ((lr & 8) << 2);
  const int aRdOff = wm * 8192 + lr * 64 + rswz;             // + i*1024 + kh*16384
  const int bRdOff = 32768 + wn * 4096 + lr * 64 + rswz;     // + j*1024 + kh*16384

#define STAGE_A(T, H, BUF) do { \
  _Pragma("unroll") for (int n2_ = 0; n2_ < 2; ++n2_) { \
    const int cc_ = wave * 2 + n2_, kh_ = cc_ >> 3, r0_ = (cc_ & 7) << 4; \
    gl_lds16(Ag + (long)((H) * 128 + r0_ + lrow) * K + ((T) * 64 + kh_ * 32 + kbs * 8), \
             lds + (BUF) * 65536 + kh_ * 16384 + ((H) * 128 + r0_) * 64 + lane * 16); } } while (0)
#define STAGE_B(T, H, BUF) do { \
  _Pragma("unroll") for (int n2_ = 0; n2_ < 2; ++n2_) { \
    const int cc_ = wave * 2 + n2_, kh_ = cc_ >> 3, r0_ = (cc_ & 7) << 4; \
    gl_lds16(Bg + (long)((H) * 128 + r0_ + lrow) * K + ((T) * 64 + kh_ * 32 + kbs * 8), \
             lds + (BUF) * 65536 + 32768 + kh_ * 16384 + ((H) * 128 + r0_) * 64 + lane * 16); } } while (0)

  f32x4 acc[8][4];
#pragma unroll
  for (int i = 0; i < 8; ++i)
#pragma unroll
    for (int j = 0; j < 4; ++j)
#pragma unroll
      for (int r = 0; r < 4; ++r) acc[i][j][r] = 0.0f;

  // ---- prologue: tile0 {Blo,Bhi,Alo,Ahi}, tile1 {Blo,Bhi,Alo} = 14 loads;
  //      wait until tile0's 8 landed, leave tile1's 6 in flight.
  STAGE_B(0, 0, 0); STAGE_B(0, 1, 0); STAGE_A(0, 0, 0); STAGE_A(0, 1, 0);
  STAGE_B(1, 0, 1); STAGE_B(1, 1, 1); STAGE_A(1, 0, 1);
  asm volatile("s_waitcnt vmcnt(6)" ::: "memory");
  __builtin_amdgcn_s_barrier();

  bf16x8 bF[4][2], aF[2][2], aG[2][2];

#define RD(P, OFF) (*(const bf16x8*)((P) + (OFF)))
#define MFMA_I(IS, A0, A1) do { \
  _Pragma("unroll") for (int j_ = 0; j_ < 4; ++j_) { \
    acc[IS][j_] = __builtin_amdgcn_mfma_f32_16x16x32_bf16((A0), bF[j_][0], acc[IS][j_], 0, 0, 0); \
    acc[IS][j_] = __builtin_amdgcn_mfma_f32_16x16x32_bf16((A1), bF[j_][1], acc[IS][j_], 0, 0, 0); } } while (0)

#define TILE(T, CUR) do { \
    const char* Ap_ = lds + (CUR) * 65536; \
    /* ---- phase 0: all B + A i{0,1}; stage A-hi(T+1) -> other buf ---- */ \
    _Pragma("unroll") for (int j_ = 0; j_ < 4; ++j_) { \
      bF[j_][0] = RD(Ap_, bRdOff + j_ * 1024); \
      bF[j_][1] = RD(Ap_, bRdOff + 16384 + j_ * 1024); } \
    aF[0][0] = RD(Ap_, aRdOff);          aF[0][1] = RD(Ap_, aRdOff + 16384); \
    aF[1][0] = RD(Ap_, aRdOff + 1024);   aF[1][1] = RD(Ap_, aRdOff + 16384 + 1024); \
    if ((T) + 1 < NT) STAGE_A((T) + 1, 1, (CUR) ^ 1); \
    __builtin_amdgcn_s_barrier(); \
    asm volatile("s_waitcnt lgkmcnt(0)" ::: "memory"); \
    __builtin_amdgcn_s_setprio(1); \
    MFMA_I(0, aF[0][0], aF[0][1]); \
    MFMA_I(1, aF[1][0], aF[1][1]); \
    __builtin_amdgcn_s_setprio(0); \
    __builtin_amdgcn_s_barrier(); \
    /* ---- phase 1: A i{2,3}; stage B-lo(T+2) -> cur (B consumed in ph0) ---- */ \
    aF[0][0] = RD(Ap_, aRdOff + 2 * 1024); aF[0][1] = RD(Ap_, aRdOff + 16384 + 2 * 1024); \
    aF[1][0] = RD(Ap_, aRdOff + 3 * 1024); aF[1][1] = RD(Ap_, aRdOff + 16384 + 3 * 1024); \
    if ((T) + 2 < NT) STAGE_B((T) + 2, 0, (CUR)); \
    __builtin_amdgcn_s_barrier(); \
    asm volatile("s_waitcnt lgkmcnt(0)" ::: "memory"); \
    __builtin_amdgcn_s_setprio(1); \
    MFMA_I(2, aF[0][0], aF[0][1]); \
    MFMA_I(3, aF[1][0], aF[1][1]); \
    __builtin_amdgcn_s_setprio(0); \
    __builtin_amdgcn_s_barrier(); \
    /* ---- phase 2: A i{4,5} + i{6,7}; stage B-hi(T+2) -> cur ---- */ \
    aF[0][0] = RD(Ap_, aRdOff + 4 * 1024); aF[0][1] = RD(Ap_, aRdOff + 16384 + 4 * 1024); \
    aF[1][0] = RD(Ap_, aRdOff + 5 * 1024); aF[1][1] = RD(Ap_, aRdOff + 16384 + 5 * 1024); \
    aG[0][0] = RD(Ap_, aRdOff + 6 * 1024); aG[0][1] = RD(Ap_, aRdOff + 16384 + 6 * 1024); \
    aG[1][0] = RD(Ap_, aRdOff + 7 * 1024); aG[1][1] = RD(Ap_, aRdOff + 16384 + 7 * 1024); \
    if ((T) + 2 < NT) STAGE_B((T) + 2, 1, (CUR)); \
    __builtin_amdgcn_s_barrier(); \
    asm volatile("s_waitcnt lgkmcnt(0)" ::: "memory"); \
    __builtin_amdgcn_s_setprio(1); \
    MFMA_I(4, aF[0][0], aF[0][1]); \
    MFMA_I(5, aF[1][0], aF[1][1]); \
    __builtin_amdgcn_s_setprio(0); \
    __builtin_amdgcn_s_barrier(); \
    /* ---- phase 3: regs ready; stage A-lo(T+2) -> cur (A consumed by ph2) ---- */ \
    if ((T) + 2 < NT) STAGE_A((T) + 2, 0, (CUR)); \
    __builtin_amdgcn_s_barrier(); \
    asm volatile("s_waitcnt lgkmcnt(0)" ::: "memory"); \
    __builtin_amdgcn_s_setprio(1); \
    MFMA_I(6, aG[0][0], aG[0][1]); \
    MFMA_I(7, aG[1][0], aG[1][1]); \
    __builtin_amdgcn_s_setprio(0); \
    if ((T) + 2 < NT)      { asm volatile("s_waitcnt vmcnt(6)" ::: "memory"); } \
    else if ((T) + 1 < NT) { asm volatile("s_waitcnt vmcnt(0)" ::: "memory"); } \
    __builtin_amdgcn_s_barrier(); \
  } while (0)

  for (int t = 0; t < NT; t += 2) {   // NT is even (16 or 64)
    TILE(t, 0);
    TILE(t + 1, 1);
  }
#undef TILE
#undef MFMA_I
#undef RD
#undef STAGE_A
#undef STAGE_B

  // C/D layout: col=lane&15, row=(lane>>4)*4+reg  [m89-verified]
#pragma unroll
  for (int i = 0; i < 8; ++i) {
#pragma unroll
    for (int j = 0; j < 4; ++j) {
#pragma unroll
      for (int r = 0; r < 4; ++r) {
        const int row = m0 + wm * 128 + i * 16 + lq * 4 + r;
        const int col = n0 + wn * 64 + j * 16 + lr;
        const long idx = (long)row * N + col;
        float v = acc[i][j][r];
        if constexpr (EPI == EPI_BF16) {
          outb[idx] = f2b(v);
        } else if constexpr (EPI == EPI_OM) {
          float rr = sigm(v + biasf[col]);
          float ls = -log1pf(expf(-vecf[col]));
          outb[idx] = f2b(-expm1f(8.0f * rr * ls));
        } else if constexpr (EPI == EPI_U) {
          float ii = sigm(v + biasf[col]);
          float om = b2f(auxb2[idx]);
          float g  = sqrtf(fmaxf(om * (2.0f - om), 1e-6f));
          outb[idx] = f2b(g * ii * b2f(auxb[idx]));
        } else if constexpr (EPI == EPI_GELU) {
          outb[idx] = f2b(gelu_f(v));
        } else if constexpr (EPI == EPI_GELU_MUL) {
          float u2 = b2f(outb[idx]);
          outb[idx] = f2b(gelu_f(v) * u2);
        } else if constexpr (EPI == EPI_X1) {
          outb[idx] = f2b(v + auxf[idx]);
        } else if constexpr (EPI == EPI_X2) {
          outf[idx] = v + b2f(auxb[idx]);
        }
      }
    }
  }
}

// ---- f32 -> bf16 cast (x4 vectorized) ----
__global__ __launch_bounds__(256)
void cast4_kernel(const float* __restrict__ in, bf16* __restrict__ out, long n4) {
  long i = (long)blockIdx.x * 256 + threadIdx.x;
  if (i < n4) {
    float4 v = reinterpret_cast<const float4*>(in)[i];
    union { bf16 h[4]; ushort4 u; } pk;
    pk.h[0] = f2b(v.x); pk.h[1] = f2b(v.y); pk.h[2] = f2b(v.z); pk.h[3] = f2b(v.w);
    reinterpret_cast<ushort4*>(out)[i] = pk.u;
  }
}

// ---- RMSNorm: one block per row (D=1024, 256 thr x 4 elems), f32 weight ----
template <typename TIN>
__global__ __launch_bounds__(256)
void rmsnorm_kernel(const TIN* __restrict__ x, const float* __restrict__ w,
                    bf16* __restrict__ out) {
  const int row = blockIdx.x;
  const int t = threadIdx.x;
  float4 v;
  if constexpr (sizeof(TIN) == 4) {
    v = reinterpret_cast<const float4*>(x + (long)row * ND)[t];
  } else {
    union { ushort4 u; bf16 h[4]; } xv;
    xv.u = reinterpret_cast<const ushort4*>(x + (long)row * ND)[t];
    v = make_float4(b2f(xv.h[0]), b2f(xv.h[1]), b2f(xv.h[2]), b2f(xv.h[3]));
  }
  float ss = v.x * v.x + v.y * v.y + v.z * v.z + v.w * v.w;
#pragma unroll
  for (int off = 32; off > 0; off >>= 1) ss += __shfl_down(ss, off, 64);
  __shared__ float red[4];
  if ((t & 63) == 0) red[t >> 6] = ss;
  __syncthreads();
  float tot = red[0] + red[1] + red[2] + red[3];
  float scale = rsqrtf(tot * (1.0f / ND) + 1.1920929e-07f);
  float4 wv = reinterpret_cast<const float4*>(w)[t];
  union { bf16 h[4]; ushort4 u; } pk;
  pk.h[0] = f2b(v.x * scale * wv.x);
  pk.h[1] = f2b(v.y * scale * wv.y);
  pk.h[2] = f2b(v.z * scale * wv.z);
  pk.h[3] = f2b(v.w * scale * wv.w);
  reinterpret_cast<ushort4*>(out + (long)row * ND)[t] = pk.u;
}

// ---- causal depthwise conv K=4 -> b1_conv (bf16) + new_conv_buf (f32 OUTPUT) ----
__global__ __launch_bounds__(256)
void conv_kernel(const bf16* __restrict__ b1, const float* __restrict__ conv_buf,
                 const float* __restrict__ conv_w, const float* __restrict__ conv_b,
                 bf16* __restrict__ out_b1c, float* __restrict__ out_newbuf) {
  const long gid = (long)blockIdx.x * 256 + threadIdx.x;   // over NM*ND
  const int d = (int)(gid & (ND - 1));
  const long bt = gid >> 10;
  const int t = (int)(bt & (NT_ - 1));
  const int b = (int)(bt >> 10);
  float acc = conv_b[d];
#pragma unroll
  for (int k = 0; k < 4; ++k) {
    const int p = t + k;
    float src = (p < 3) ? conv_buf[((long)b * 3 + p) * ND + d]
                        : b2f(b1[((long)b * NT_ + (p - 3)) * ND + d]);
    acc = fmaf(conv_w[d * 4 + k], src, acc);
  }
  out_b1c[gid] = f2b(acc);
  if (t >= NT_ - 3)
    out_newbuf[((long)b * 3 + (t - (NT_ - 3))) * ND + d] = b2f(b1[gid]);
}

// ---- sequential scan over T (f32 state, om-form), fused with b2 product ----
__global__ __launch_bounds__(256)
void scan_kernel(const bf16* __restrict__ om, const bf16* __restrict__ u,
                 const bf16* __restrict__ b2, const float* __restrict__ h0,
                 bf16* __restrict__ prod, float* __restrict__ newh) {
  const int gid = blockIdx.x * 256 + threadIdx.x;  // NB*ND = 16384 chains
  const int d = gid & (ND - 1);
  const int b = gid >> 10;
  float h = h0[gid];
  const long base = (long)b * NT_ * ND + d;
#pragma unroll 8
  for (int t = 0; t < NT_; ++t) {
    const long idx = base + (long)t * ND;
    h = fmaf(-b2f(om[idx]), h, h) + b2f(u[idx]);
    prod[idx] = f2b(h * b2f(b2[idx]));
  }
  newh[gid] = h;   // f32 OUTPUT
}

// ---- launcher ----
extern "C" void kernel_launch(void* const* d_in, const int* in_sizes, int n_in,
                              void* d_out, int out_size, void* d_ws, size_t ws_size,
                              hipStream_t stream) {
  const float* x_seq    = (const float*)d_in[0];
  const float* h0       = (const float*)d_in[1];
  const float* conv_buf = (const float*)d_in[2];
  const float* norm1_w  = (const float*)d_in[3];
  const float* W1       = (const float*)d_in[4];
  const float* conv_w   = (const float*)d_in[5];
  const float* conv_b   = (const float*)d_in[6];
  const float* Wa       = (const float*)d_in[7];
  const float* ba       = (const float*)d_in[8];
  const float* Wx       = (const float*)d_in[9];
  const float* bx       = (const float*)d_in[10];
  const float* loglam   = (const float*)d_in[11];
  const float* W2       = (const float*)d_in[12];
  const float* Wout     = (const float*)d_in[13];
  const float* norm2_w  = (const float*)d_in[14];
  const float* Wg       = (const float*)d_in[15];
  const float* Wu       = (const float*)d_in[16];
  const float* Wo       = (const float*)d_in[17];

  // ---- workspace arena: exactly 224 MiB (proven-safe layout) ----
  char* ws = (char*)d_ws;
  bf16* normed = (bf16*)(ws);
  bf16* b1buf  = (bf16*)(ws + (32L  << 20));   // b1, then prod
  bf16* b1cbuf = (bf16*)(ws + (64L  << 20));   // b1_conv
  bf16* Woutb  = (bf16*)(ws + (64L  << 20));   // overlay after b1_conv dies
  bf16* ombuf  = (bf16*)(ws + (96L  << 20));   // om = 1-a
  bf16* ubuf   = (bf16*)(ws + (128L << 20));   // u
  bf16* x1buf  = (bf16*)(ws + (160L << 20));   // b2, then x1
  bf16* b2buf  = x1buf;
  bf16* bigbuf = (bf16*)(ws + (32L  << 20));   // 128M overlay
  bf16* W1b    = (bf16*)(ws + (192L << 20));
  bf16* Wab    = (bf16*)(ws + (194L << 20));
  bf16* Wxb    = (bf16*)(ws + (196L << 20));
  bf16* W2b    = (bf16*)(ws + (198L << 20));
  bf16* Wgb    = (bf16*)(ws + (200L << 20));
  bf16* Wub    = (bf16*)(ws + (208L << 20));
  bf16* Wob    = (bf16*)(ws + (216L << 20));

  float* out_x2 = (float*)d_out;                 // (B,T,D) f32
  float* out_h  = out_x2 + (long)NM * ND;        // (B,D)   f32
  float* out_cb = out_h + NB * ND;               // (B,3,D) f32

  const dim3 blk(256);
  const dim3 blk512(512);
  const dim3 gD256((NM / 256) * (ND / 256));   // 64*4  = 256 blocks
  const dim3 gH256((NM / 256) * (NH / 256));   // 64*16 = 1024 blocks

  // upfront weight casts (Wout deferred: its slot holds b1_conv until K5)
  cast4_kernel<<<dim3(1024), blk, 0, stream>>>(W1, W1b, 262144);
  cast4_kernel<<<dim3(1024), blk, 0, stream>>>(Wa, Wab, 262144);
  cast4_kernel<<<dim3(1024), blk, 0, stream>>>(Wx, Wxb, 262144);
  cast4_kernel<<<dim3(1024), blk, 0, stream>>>(W2, W2b, 262144);
  cast4_kernel<<<dim3(4096), blk, 0, stream>>>(Wg, Wgb, 1048576);
  cast4_kernel<<<dim3(4096), blk, 0, stream>>>(Wu, Wub, 1048576);
  cast4_kernel<<<dim3(4096), blk, 0, stream>>>(Wo, Wob, 1048576);

  // K1: normed = rmsnorm(x_seq, norm1_w)
  rmsnorm_kernel<float><<<dim3(NM), blk, 0, stream>>>(x_seq, norm1_w, normed);
  // K2: b1 = normed @ W1^T
  gemm256<EPI_BF16><<<gD256, blk512, 0, stream>>>(normed, W1b, NM, ND, ND,
      nullptr, nullptr, nullptr, nullptr, nullptr, nullptr, b1buf);
  // K3: causal conv -> b1_conv, new_conv_buf (f32 out)
  conv_kernel<<<dim3((NM * ND) / 256), blk, 0, stream>>>(b1buf, conv_buf, conv_w, conv_b,
      b1cbuf, out_cb);
  // K4: om = 1 - exp(8*sigmoid(b1c@Wa^T+ba)*logsig(lam))
  gemm256<EPI_OM><<<gD256, blk512, 0, stream>>>(b1cbuf, Wab, NM, ND, ND,
      ba, loglam, nullptr, nullptr, nullptr, nullptr, ombuf);
  // K5: u = gate(om) * sigmoid(b1c@Wx^T+bx) * b1c
  gemm256<EPI_U><<<gD256, blk512, 0, stream>>>(b1cbuf, Wxb, NM, ND, ND,
      bx, nullptr, b1cbuf, ombuf, nullptr, nullptr, ubuf);
  // K6: b2 = gelu(normed @ W2^T)
  gemm256<EPI_GELU><<<gD256, blk512, 0, stream>>>(normed, W2b, NM, ND, ND,
      nullptr, nullptr, nullptr, nullptr, nullptr, nullptr, b2buf);
  // K7: scan; prod = h*b2 (into b1 slot), new_h (f32 out)
  scan_kernel<<<dim3(NB * ND / 256), blk, 0, stream>>>(ombuf, ubuf, b2buf, h0, b1buf, out_h);
  // late cast: Wout into b1_conv's dead slot
  cast4_kernel<<<dim3(1024), blk, 0, stream>>>(Wout, Woutb, 262144);
  // K8: x1 = x_seq + prod @ Wout^T  (bf16, into b2's dead slot)
  gemm256<EPI_X1><<<gD256, blk512, 0, stream>>>(b1buf, Woutb, NM, ND, ND,
      nullptr, nullptr, nullptr, nullptr, x_seq, nullptr, x1buf);
  // K9: n2 = rmsnorm(x1, norm2_w)
  rmsnorm_kernel<bf16><<<dim3(NM), blk, 0, stream>>>(x1buf, norm2_w, normed);
  // K10: u2 = n2 @ Wu^T -> big
  gemm256<EPI_BF16><<<gH256, blk512, 0, stream>>>(normed, Wub, NM, NH, ND,
      nullptr, nullptr, nullptr, nullptr, nullptr, nullptr, bigbuf);
  // K11: big = gelu(n2 @ Wg^T) * big  (in place)
  gemm256<EPI_GELU_MUL><<<gH256, blk512, 0, stream>>>(normed, Wgb, NM, NH, ND,
      nullptr, nullptr, nullptr, nullptr, nullptr, nullptr, bigbuf);
  // K12: x2 = x1 + big @ Wo^T -> d_out (f32)
  gemm256<EPI_X2><<<gD256, blk512, 0, stream>>>(bigbuf, Wob, NM, ND, NH,
      nullptr, nullptr, x1buf, nullptr, nullptr, out_x2, nullptr);
}